// Round 6
// baseline (95.689 us; speedup 1.0000x reference)
//
#include <hip/hip_runtime.h>

// out[b,e,j] = bias[j] + sum_k weight[k,j] * y[b, e+k-7, j]
// y[b,e',j]  = sum_{i<=j} x[b,e',i] * dv^(j-i)   (decayed prefix scan over features)
// dv = clip(decay_value[1], 0.9, 1.0); y rows with e' < 0 are zero.
//
// R6: register-window kernel, tuned for TLP. R5 (SE=8, 2048 waves) was 97%
// stall: only 2 waves/SIMD (grid-limited) and wv[64]+a[64] regs serialized the
// row unroll. Now SE=4 -> 4096 waves = 4 waves/SIMD; weights live in LDS
// (staged once, single barrier at start) instead of 64 VGPRs; launch_bounds
// caps VGPR at 128 so all 4 waves/SIMD are resident. Halo x re-reads (2.75x)
// are L3-served; HBM stays at the 67 MB compulsory floor.

#define B_    8
#define E_    2048
#define DIM_  512
#define K_    8
#define SE_   4                     // output rows per wave
#define NR_   (SE_ + K_ - 1)        // 11 scan rows per wave

__global__ __launch_bounds__(256, 4) void krl_win(
    const float* __restrict__ x,
    const float* __restrict__ weight,
    const float* __restrict__ bias,
    const float* __restrict__ decay,
    float* __restrict__ out)
{
    __shared__ float wlds[K_][DIM_];     // 16 KB
    __shared__ float blds[DIM_];         // 2 KB

    const int t    = threadIdx.x;
    const int lane = t & 63;
    const int wave = t >> 6;

    // ---- stage weights + bias to LDS (once), then a single barrier ----
    {
        const float4* wsrc = (const float4*)weight;
        float4*       wdst = (float4*)&wlds[0][0];
        #pragma unroll
        for (int i = 0; i < 4; ++i) wdst[t + 256 * i] = wsrc[t + 256 * i];
        if (t < 128) ((float4*)blds)[t] = ((const float4*)bias)[t];
    }

    const int wid  = blockIdx.x * 4 + wave;      // [0, 4096)
    const int b    = wid >> 9;                   // E_/SE_ = 512 strips per b
    const int e0   = (wid & 511) << 2;

    float dv = decay[1];
    dv = fminf(fmaxf(dv, 0.9f), 1.0f);
    const float dv2 = dv * dv;
    const float dv4 = dv2 * dv2;
    const float dv8 = dv4 * dv4;

    const int jf = lane * 8;                     // 8 contiguous features per lane

    float a[SE_][8];
    #pragma unroll
    for (int m = 0; m < SE_; ++m)
        #pragma unroll
        for (int j = 0; j < 8; ++j) a[m][j] = 0.f;

    const float* xb = x + (size_t)b * E_ * DIM_ + jf;
    float*       ob = out + ((size_t)b * E_ + e0) * DIM_ + jf;

    __syncthreads();                              // weights visible

    #pragma unroll
    for (int r = 0; r < NR_; ++r) {
        const int eg = e0 - (K_ - 1) + r;        // scan-row index in E
        if (eg >= 0) {                           // wave-uniform (false only near e0=0)
            const float4* xp = (const float4*)(xb + (size_t)eg * DIM_);
            const float4 a0 = xp[0];
            const float4 a1 = xp[1];
            const float xv[8] = {a0.x, a0.y, a0.z, a0.w, a1.x, a1.y, a1.z, a1.w};

            // lane-local decayed scan over 8 contiguous features
            float tl[8];
            tl[0] = xv[0];
            #pragma unroll
            for (int m = 1; m < 8; ++m) tl[m] = fmaf(dv, tl[m - 1], xv[m]);

            // cross-lane: Y_l = T_l + dv^8 * Y_{l-1} (Kogge-Stone over 64 lanes)
            float v  = tl[7];
            float ap = dv8;
            #pragma unroll
            for (int off = 1; off < 64; off <<= 1) {
                float up = __shfl_up(v, off, 64);
                if (lane >= off) v = fmaf(ap, up, v);
                ap *= ap;
            }
            float carry = __shfl_up(v, 1, 64);   // y[jf - 1]
            if (lane == 0) carry = 0.f;
            float dp = dv;
            #pragma unroll
            for (int m = 0; m < 8; ++m) { tl[m] = fmaf(dp, carry, tl[m]); dp *= dv; }

            // fold y-row r into pending accumulators: output e0+m takes tap r-m
            #pragma unroll
            for (int m = 0; m < SE_; ++m) {
                if (m <= r && r - m <= K_ - 1) { // static after unroll
                    const int k = r - m;
                    const float4 w0 = *(const float4*)(&wlds[k][jf]);
                    const float4 w1 = *(const float4*)(&wlds[k][jf + 4]);
                    a[m][0] = fmaf(w0.x, tl[0], a[m][0]);
                    a[m][1] = fmaf(w0.y, tl[1], a[m][1]);
                    a[m][2] = fmaf(w0.z, tl[2], a[m][2]);
                    a[m][3] = fmaf(w0.w, tl[3], a[m][3]);
                    a[m][4] = fmaf(w1.x, tl[4], a[m][4]);
                    a[m][5] = fmaf(w1.y, tl[5], a[m][5]);
                    a[m][6] = fmaf(w1.z, tl[6], a[m][6]);
                    a[m][7] = fmaf(w1.w, tl[7], a[m][7]);
                }
            }
        }
        // output row e0 + (r-7) is complete after its last tap (scan row r)
        if (r >= K_ - 1) {
            const int m = r - (K_ - 1);
            const float4 b0 = *(const float4*)(&blds[jf]);
            const float4 b1 = *(const float4*)(&blds[jf + 4]);
            float4 o0 = make_float4(a[m][0] + b0.x, a[m][1] + b0.y,
                                    a[m][2] + b0.z, a[m][3] + b0.w);
            float4 o1 = make_float4(a[m][4] + b1.x, a[m][5] + b1.y,
                                    a[m][6] + b1.z, a[m][7] + b1.w);
            *(float4*)(ob + (size_t)m * DIM_)     = o0;
            *(float4*)(ob + (size_t)m * DIM_ + 4) = o1;
        }
    }
}

extern "C" void kernel_launch(void* const* d_in, const int* in_sizes, int n_in,
                              void* d_out, int out_size, void* d_ws, size_t ws_size,
                              hipStream_t stream) {
    const float* x      = (const float*)d_in[0];
    const float* weight = (const float*)d_in[1];
    const float* bias   = (const float*)d_in[2];
    const float* decay  = (const float*)d_in[3];
    float* out = (float*)d_out;

    // 4096 waves = 1024 blocks x 4 waves = exactly 4 blocks/CU, one round.
    krl_win<<<dim3((B_ * (E_ / SE_)) / 4), dim3(256), 0, stream>>>(
        x, weight, bias, decay, out);
}